// Round 16
// baseline (310.013 us; speedup 1.0000x reference)
//
#include <hip/hip_runtime.h>

#define N_NODES  500000
#define HIDDEN   256
#define N_GRAPHS 8192
#define NWAVES   (N_NODES / 16)          // 31250 windows (N_NODES % 16 == 0)
#define NBLK     ((NWAVES + 3) / 4)      // 7813 blocks of 4 waves
#define PROW     260                     // 256 num + 1 den + pad

typedef float f32x4 __attribute__((ext_vector_type(4)));
typedef short s16x8 __attribute__((ext_vector_type(8)));

__device__ __forceinline__ unsigned short f2bf(float f) {
    unsigned int u = __float_as_uint(f);
    u += 0x7fffu + ((u >> 16) & 1u);   // RNE round to bf16
    return (unsigned short)(u >> 16);
}

// Pack W1 [K=256][N=256] fp32 into bf16 B-fragments.
// slot = (q*8 + kt)*4 + p ; nt = q*4 + p
// w1pack[(slot*64 + lane)*8 + j] = bf16( W1[kt*32 + (lane>>4)*8 + j][nt*16 + (lane&15)] )
__global__ void prep_w1_kernel(const float* __restrict__ W1,
                               unsigned short* __restrict__ w1pack) {
    int tid  = blockIdx.x * 256 + threadIdx.x;   // 0..8191
    int lane = tid & 63;
    int slot = tid >> 6;                         // 0..127
    int wv   = slot >> 5;
    int kt   = (slot >> 2) & 7;
    int ntp  = slot & 3;
    int nt   = wv * 4 + ntp;
    int krow = kt * 32 + ((lane >> 4) & 3) * 8;
    int col  = nt * 16 + (lane & 15);
    unsigned short tmp[8];
#pragma unroll
    for (int j = 0; j < 8; ++j)
        tmp[j] = f2bf(W1[(size_t)(krow + j) * 256 + col]);
    *(uint4*)(w1pack + (size_t)tid * 8) = *(const uint4*)tmp;
}

// offsEnd[g] = lower_bound(batch, g+1)
__global__ void offsets_kernel(const int* __restrict__ batch,
                               int* __restrict__ offsEnd) {
    int g = blockIdx.x * 256 + threadIdx.x;
    if (g >= N_GRAPHS) return;
    int lo = 0, hi = N_NODES;
    while (lo < hi) {
        int mid = (lo + hi) >> 1;
        if (batch[mid] < g + 1) lo = mid + 1; else hi = mid;
    }
    offsEnd[g] = lo;
}

// Wave-autonomous fused kernel: each wave owns a 16-node window. No LDS, no
// barriers. A-fragments load straight from global x (fp32 -> bf16 in-reg);
// B streams from L2-hot w1pack; 16-lane butterfly for logits; windowed
// segment walk with direct-out / preW / sufW partials (round-13 logic).
__launch_bounds__(256, 4)
__global__ void fused_wave(const float* __restrict__ x,
                           const int*   __restrict__ batch,
                           const float* __restrict__ b1,
                           const float* __restrict__ W2,
                           const float* __restrict__ b2,
                           const unsigned short* __restrict__ w1pack,
                           float* __restrict__ preW,
                           float* __restrict__ sufW,
                           float* __restrict__ out) {
    const int lane = threadIdx.x & 63;
    const int cl   = lane & 15;
    const int kgrp = lane >> 4;
    const int wid  = blockIdx.x * 4 + (threadIdx.x >> 6);   // global window id
    if (wid >= NWAVES) return;
    const int ws = wid * 16;                                 // window start row

    // ---- GEMM: A direct from global (row ws+cl), B from w1pack ----
    f32x4 acc[4][4];
#pragma unroll
    for (int q = 0; q < 4; ++q)
#pragma unroll
        for (int p = 0; p < 4; ++p)
            acc[q][p] = (f32x4){0.f, 0.f, 0.f, 0.f};

    const float* arow = x + (size_t)(ws + cl) * HIDDEN + kgrp * 8;
#pragma unroll
    for (int kt = 0; kt < 8; ++kt) {
        f32x4 a0 = *(const f32x4*)(arow + kt * 32);
        f32x4 a1 = *(const f32x4*)(arow + kt * 32 + 4);
        s16x8 af;
        af[0] = (short)f2bf(a0[0]); af[1] = (short)f2bf(a0[1]);
        af[2] = (short)f2bf(a0[2]); af[3] = (short)f2bf(a0[3]);
        af[4] = (short)f2bf(a1[0]); af[5] = (short)f2bf(a1[1]);
        af[6] = (short)f2bf(a1[2]); af[7] = (short)f2bf(a1[3]);
#pragma unroll
        for (int q = 0; q < 4; ++q) {
            s16x8 bf[4];
#pragma unroll
            for (int p = 0; p < 4; ++p)
                bf[p] = *(const s16x8*)(w1pack +
                    ((size_t)(((q * 8 + kt) * 4 + p) * 64 + lane) << 3));
#pragma unroll
            for (int p = 0; p < 4; ++p)
                acc[q][p] = __builtin_amdgcn_mfma_f32_16x16x32_bf16(
                    af, bf[p], acc[q][p], 0, 0, 0);
        }
    }

    // ---- tanh + logit partial over this lane's 16 cols (nt*16+cl) ----
    float sj[4] = {0.f, 0.f, 0.f, 0.f};
#pragma unroll
    for (int q = 0; q < 4; ++q)
#pragma unroll
        for (int p = 0; p < 4; ++p) {
            int nt = q * 4 + p;
            float bb = b1[nt * 16 + cl];
            float ww = W2[nt * 16 + cl];
#pragma unroll
            for (int j = 0; j < 4; ++j) {
                float h = acc[q][p][j] + bb;
                h = fminf(fmaxf(h, -15.f), 15.f);
                float e2 = __expf(2.f * h);
                float th = (e2 - 1.f) * __builtin_amdgcn_rcpf(e2 + 1.f);
                sj[j] += th * ww;
            }
        }
    // reduce across the 16 cl lanes within each kgrp group
#pragma unroll
    for (int m = 1; m < 16; m <<= 1)
#pragma unroll
        for (int j = 0; j < 4; ++j)
            sj[j] += __shfl_xor(sj[j], m, 64);
    const float b2v = b2[0];
    float ev[4];
#pragma unroll
    for (int j = 0; j < 4; ++j)
        ev[j] = __expf(sj[j] + b2v);   // e for row ws + kgrp*4 + j

    // ---- windowed segment walk (round-13 validated logic) ----
    int bval = batch[ws + cl];
    const int gfirst = __shfl(bval, 0, 64);
    const int glast  = __shfl(bval, 15, 64);
    const bool eb = (ws > 0) && (batch[ws - 1] == gfirst);            // extends back
    const bool ef = (ws + 16 < N_NODES) && (batch[ws + 16] == glast); // extends fwd

    f32x4 accv = {0.f, 0.f, 0.f, 0.f};
    float accden = 0.f;
    int gcur = gfirst, sl = 0;
#pragma unroll
    for (int r = 0; r < 16; ++r) {
        int   g  = __shfl(bval, r, 64);
        float er = __shfl(ev[r & 3], (r >> 2) * 16, 64);
        if (g != gcur) {                     // wave-uniform flush (not final)
            bool sb = (sl == 0) && eb;
            if (!sb) {                       // fully inside window -> final
                float d = accden + 1e-8f;
                f32x4 res;
                res[0] = accv[0] / d; res[1] = accv[1] / d;
                res[2] = accv[2] / d; res[3] = accv[3] / d;
                *(f32x4*)(out + (size_t)gcur * HIDDEN + lane * 4) = res;
            } else {                         // continues from prev window
                *(f32x4*)(preW + (size_t)wid * PROW + lane * 4) = accv;
                if (lane == 0) preW[(size_t)wid * PROW + 256] = accden;
            }
            accv = (f32x4){0.f, 0.f, 0.f, 0.f};
            accden = 0.f;
            gcur = g; sl = r;
        }
        f32x4 xv = *(const f32x4*)(x + (size_t)(ws + r) * HIDDEN + lane * 4);
        accv += er * xv;
        accden += er;
    }
    {   // final flush
        bool sb = (sl == 0) && eb;
        if (!sb && !ef) {                    // fully inside window
            float d = accden + 1e-8f;
            f32x4 res;
            res[0] = accv[0] / d; res[1] = accv[1] / d;
            res[2] = accv[2] / d; res[3] = accv[3] / d;
            *(f32x4*)(out + (size_t)gcur * HIDDEN + lane * 4) = res;
        } else if (!sb && sl > 0) {          // starts mid-window, continues fwd
            *(f32x4*)(sufW + (size_t)wid * PROW + lane * 4) = accv;
            if (lane == 0) sufW[(size_t)wid * PROW + 256] = accden;
        } else {                             // covers window start
            *(f32x4*)(preW + (size_t)wid * PROW + lane * 4) = accv;
            if (lane == 0) preW[(size_t)wid * PROW + 256] = accden;
        }
    }
}

// Combine: one wave per graph. Straddlers (w0<w1): sum window partials.
// Empty graphs: zeros. Single-window graphs were direct-written by fused_wave.
__launch_bounds__(256)
__global__ void combine_kernel(const float* __restrict__ preW,
                               const float* __restrict__ sufW,
                               const int* __restrict__ offsEnd,
                               float* __restrict__ out) {
    const int g    = blockIdx.x * 4 + (threadIdx.x >> 6);
    const int lane = threadIdx.x & 63;
    if (g >= N_GRAPHS) return;
    const int s = (g == 0) ? 0 : offsEnd[g - 1];
    const int e = offsEnd[g];
    if (e == s) {                                // empty graph -> zeros
        *(f32x4*)(out + (size_t)g * HIDDEN + lane * 4) = (f32x4){0.f, 0.f, 0.f, 0.f};
        return;
    }
    const int w0 = s >> 4, w1 = (e - 1) >> 4;
    if (w0 == w1) return;                        // direct-written

    const float* row = (s > (w0 << 4)) ? sufW + (size_t)w0 * PROW
                                       : preW + (size_t)w0 * PROW;
    f32x4 acc = *(const f32x4*)(row + lane * 4);
    float den = row[256];
    for (int w = w0 + 1; w <= w1; ++w) {
        const float* pr = preW + (size_t)w * PROW;
        acc += *(const f32x4*)(pr + lane * 4);
        den += pr[256];
    }
    float d = den + 1e-8f;
    f32x4 res;
    res[0] = acc[0] / d; res[1] = acc[1] / d;
    res[2] = acc[2] / d; res[3] = acc[3] / d;
    *(f32x4*)(out + (size_t)g * HIDDEN + lane * 4) = res;
}

extern "C" void kernel_launch(void* const* d_in, const int* in_sizes, int n_in,
                              void* d_out, int out_size, void* d_ws, size_t ws_size,
                              hipStream_t stream) {
    const float* x     = (const float*)d_in[0];
    const int*   batch = (const int*)d_in[1];
    const float* W1    = (const float*)d_in[2];
    const float* b1    = (const float*)d_in[3];
    const float* W2    = (const float*)d_in[4];
    const float* b2    = (const float*)d_in[5];
    float* out = (float*)d_out;

    unsigned short* w1pack = (unsigned short*)d_ws;                  // 128 KiB
    int*   offsEnd = (int*)((char*)d_ws + 131072);                   // 32 KiB
    float* preW    = (float*)((char*)d_ws + 163840);                 // 32.5 MB
    float* sufW    = (float*)((char*)d_ws + 163840 + (size_t)NWAVES * PROW * 4);

    prep_w1_kernel<<<32, 256, 0, stream>>>(W1, w1pack);
    offsets_kernel<<<32, 256, 0, stream>>>(batch, offsEnd);

    fused_wave<<<NBLK, 256, 0, stream>>>(x, batch, b1, W2, b2, w1pack,
                                         preW, sufW, out);
    combine_kernel<<<(N_GRAPHS + 3) / 4, 256, 0, stream>>>(preW, sufW, offsEnd, out);
}